// Round 2
// baseline (619.607 us; speedup 1.0000x reference)
//
#include <hip/hip_runtime.h>
#include <math.h>

// Problem constants (match reference)
#define UU 500000
#define II 500000
#define DD 64
#define KK 32
#define BB 8192
#define NNEG 128

typedef float v4f __attribute__((ext_vector_type(4)));

__device__ __forceinline__ float softplus_f(float x) {
    return fmaxf(x, 0.0f) + log1pf(expf(-fabsf(x)));
}

__device__ __forceinline__ float waveReduceSum(float v) {
#pragma unroll
    for (int off = 32; off > 0; off >>= 1) v += __shfl_xor(v, off, 64);
    return v;
}

__device__ __forceinline__ unsigned int bf16pack2(float lo, float hi) {
    // round-to-nearest-even bf16, packed pair (lo in low 16)
    unsigned int ul = __float_as_uint(lo);
    ul += 0x7FFFu + ((ul >> 16) & 1u);
    unsigned int uh = __float_as_uint(hi);
    uh += 0x7FFFu + ((uh >> 16) & 1u);
    return (ul >> 16) | (uh & 0xFFFF0000u);
}

// ===========================================================================
// K1: norm over all params (fp32) + convert item_emb -> bf16 table in d_ws.
// Pure streaming, all CUs. 4096 blocks x 256. (Round-0 proven version.)
// ===========================================================================
__global__ __launch_bounds__(256) void norm_convert_kernel(
    const float* __restrict__ user_emb, const float* __restrict__ item_emb,
    unsigned int* __restrict__ bfit,    // II*DD bf16 = II*DD/2 uints
    const float* __restrict__ mse_u_w, const float* __restrict__ mse_u_b,
    const float* __restrict__ mse_i_w, const float* __restrict__ mse_i_b,
    const float* __restrict__ fc1_w1, const float* __restrict__ fc1_b1,
    const float* __restrict__ fc1_w2, const float* __restrict__ fc1_b2,
    float* __restrict__ acc)
{
    const size_t tid = (size_t)blockIdx.x * blockDim.x + threadIdx.x;
    const size_t st  = (size_t)gridDim.x * blockDim.x;
    float s = 0.f;

    // ---- item_emb: read fp32 (NT), accumulate squares, write bf16 ----
    {
        const size_t npair = (size_t)II * DD / 8;   // 4M: each iter = 2 float4 -> one uint4
        const v4f* it4 = (const v4f*)item_emb;
        uint4* out4 = (uint4*)bfit;
        for (size_t k = tid; k < npair; k += st) {
            v4f a = __builtin_nontemporal_load(&it4[2 * k]);
            v4f b = __builtin_nontemporal_load(&it4[2 * k + 1]);
            s += a.x*a.x + a.y*a.y + a.z*a.z + a.w*a.w;
            s += b.x*b.x + b.y*b.y + b.z*b.z + b.w*b.w;
            uint4 w;
            w.x = bf16pack2(a.x, a.y);
            w.y = bf16pack2(a.z, a.w);
            w.z = bf16pack2(b.x, b.y);
            w.w = bf16pack2(b.z, b.w);
            out4[k] = w;   // normal store: want it L2/L3 resident for K2
        }
    }
    // ---- user_emb: squares only ----
    {
        const size_t n4 = (size_t)UU * DD / 4;
        const v4f* a = (const v4f*)user_emb;
        for (size_t i = tid; i < n4; i += st) {
            v4f x = __builtin_nontemporal_load(&a[i]);
            s += x.x*x.x + x.y*x.y + x.z*x.z + x.w*x.w;
        }
    }
    // ---- small params ----
    for (size_t i = tid; i < (size_t)DD * DD; i += st)
        s += mse_u_w[i] * mse_u_w[i] + mse_i_w[i] * mse_i_w[i];
    for (size_t i = tid; i < (size_t)DD * 2 * DD; i += st)
        s += fc1_w1[i] * fc1_w1[i];
    for (size_t i = tid; i < (size_t)DD; i += st)
        s += mse_u_b[i] * mse_u_b[i] + mse_i_b[i] * mse_i_b[i]
           + fc1_b1[i] * fc1_b1[i] + fc1_w2[i] * fc1_w2[i];
    if (tid == 0) s += fc1_b2[0] * fc1_b2[0];

    s = waveReduceSum(s);
    __shared__ float red[4];
    if ((threadIdx.x & 63) == 0) red[threadIdx.x >> 6] = s;
    __syncthreads();
    if (threadIdx.x == 0)
        atomicAdd(&acc[2], red[0] + red[1] + red[2] + red[3]);
}

// ===========================================================================
// K2: gather loss_L + loss_I from bf16 table, fused mse + ticket finalize.
// TWO waves per b (half 0: groups 0-4 + pos + mse; half 1: groups 5-9).
// Grid = BB/2 blocks -> 2x blocks of round-0 for backfill + shorter chains.
// Round-0 proven gather layout: 4 lanes/item, depth-3 ring, VGPR<=64 forced.
// ===========================================================================
__global__ __launch_bounds__(256, 8) void gather_split_kernel(
    const int* __restrict__ users, const int* __restrict__ pos_items,
    const int* __restrict__ neg_items, const float* __restrict__ rpkms,
    const float* __restrict__ user_emb, const float* __restrict__ item_emb,
    const unsigned int* __restrict__ bfit,
    const float* __restrict__ beta_uD, const float* __restrict__ beta_iD,
    const int* __restrict__ ii_nbr, const float* __restrict__ ii_con,
    const float* __restrict__ mse_u_w, const float* __restrict__ mse_u_b,
    const float* __restrict__ mse_i_w, const float* __restrict__ mse_i_b,
    float* __restrict__ acc, unsigned int* __restrict__ cnt,
    float* __restrict__ out)
{
    const int wave = threadIdx.x >> 6;
    const int lane = threadIdx.x & 63;
    const int pair = wave >> 1;          // which b within block (0/1)
    const int half = wave & 1;           // which group-half this wave owns
    const int b = blockIdx.x * 2 + pair;

    const int u_idx = users[b];
    const int p_idx = pos_items[b];
    const float u_reg = user_emb[(size_t)u_idx * DD + lane];
    const float bu = beta_uD[u_idx];

    __shared__ float sU[4][DD];
    __shared__ float sP[2][DD];
    sU[wave][lane] = u_reg;    // wave-synchronous (each wave its own copy)

    const int q  = lane & 3;   // quarter within item
    const int li = lane >> 2;  // item within 16-item group

    // lane's u fragment: dims [q*16, q*16+16)
    float4 uv[4];
#pragma unroll
    for (int j = 0; j < 4; ++j)
        uv[j] = *(const float4*)&sU[wave][q * 16 + j * 4];

    float accL = 0.f, accI = 0.f, accM = 0.f;

    // ---- pos score (fp32 exact), half-0 wave only ----
    if (half == 0) {
        const float p_reg = item_emb[(size_t)p_idx * DD + lane];
        sP[pair][lane] = p_reg;          // wave-synchronous, same wave reads later
        const float pos_dot = waveReduceSum(u_reg * p_reg);
        if (lane == 0)
            accL += (1e-6f + bu * beta_iD[p_idx]) * softplus_f(-pos_dot);
    }

    // ---- preload indices/weights (lane-resident, broadcast via shfl) ----
    const int i0 = neg_items[(size_t)b * NNEG + lane];
    const int i1 = neg_items[(size_t)b * NNEG + 64 + lane];
    const float bn0 = beta_iD[i0];
    const float bn1 = beta_iD[i1];
    int nbv = 0; float simv = 0.f;
    if (lane < KK) {
        nbv  = ii_nbr[(size_t)p_idx * KK + lane];
        simv = ii_con[(size_t)p_idx * KK + lane];
    }

    const float negscale4 = 0.25f * (200.0f / (float)NNEG);

    // ring buffers for pipelined gather (depth 3) — round-0 proven
    uint4 rg[3][2];
    float rw[3];

#define PREP(g, slot)                                                          \
    {                                                                          \
        int idx; float w;                                                      \
        if ((g) < 4)      { idx = __shfl(i0, (g) * 16 + li, 64);               \
                            w   = __shfl(bn0, (g) * 16 + li, 64); }            \
        else if ((g) < 8) { idx = __shfl(i1, ((g) - 4) * 16 + li, 64);         \
                            w   = __shfl(bn1, ((g) - 4) * 16 + li, 64); }      \
        else              { idx = __shfl(nbv, ((g) - 8) * 16 + li, 64);        \
                            w   = __shfl(simv, ((g) - 8) * 16 + li, 64); }     \
        const uint4* row = (const uint4*)(bfit + (size_t)idx * (DD / 2));      \
        rg[slot][0] = row[q * 2];                                              \
        rg[slot][1] = row[q * 2 + 1];                                          \
        rw[slot] = w;                                                          \
    }

#define DOT8(wv, ua, ub, d)                                                    \
    {                                                                          \
        d = fmaf(__uint_as_float((wv).x << 16), ua.x, d);                      \
        d = fmaf(__uint_as_float((wv).x & 0xFFFF0000u), ua.y, d);              \
        d = fmaf(__uint_as_float((wv).y << 16), ua.z, d);                      \
        d = fmaf(__uint_as_float((wv).y & 0xFFFF0000u), ua.w, d);              \
        d = fmaf(__uint_as_float((wv).z << 16), ub.x, d);                      \
        d = fmaf(__uint_as_float((wv).z & 0xFFFF0000u), ub.y, d);              \
        d = fmaf(__uint_as_float((wv).w << 16), ub.z, d);                      \
        d = fmaf(__uint_as_float((wv).w & 0xFFFF0000u), ub.w, d);              \
    }

#define CONSUME(g, slot)                                                       \
    {                                                                          \
        float dot = 0.f;                                                       \
        DOT8(rg[slot][0], uv[0], uv[1], dot);                                  \
        DOT8(rg[slot][1], uv[2], uv[3], dot);                                  \
        dot += __shfl_xor(dot, 1, 64);                                         \
        dot += __shfl_xor(dot, 2, 64);                                         \
        if ((g) < 8) accL += negscale4 * (1e-6f + bu * rw[slot]) * softplus_f(dot); \
        else         accI += 0.25f * rw[slot] * softplus_f(-dot);              \
    }

    if (half == 0) {
        PREP(0, 0); PREP(1, 1); PREP(2, 2);
        CONSUME(0, 0); PREP(3, 0);
        CONSUME(1, 1); PREP(4, 1);
        CONSUME(2, 2);
        CONSUME(3, 0);
        CONSUME(4, 1);
    } else {
        PREP(5, 0); PREP(6, 1); PREP(7, 2);
        CONSUME(5, 0); PREP(8, 0);
        CONSUME(6, 1); PREP(9, 1);
        CONSUME(7, 2);
        CONSUME(8, 0);
        CONSUME(9, 1);
    }
#undef PREP
#undef DOT8
#undef CONSUME

    // ---- fused mse (half-0 wave only; sU/sP written by this same wave) ----
    if (half == 0) {
        float4 pv[4];
#pragma unroll
        for (int j = 0; j < 4; ++j)
            pv[j] = *(const float4*)&sP[pair][q * 16 + j * 4];
        float pq = 0.f;
#pragma unroll
        for (int g = 0; g < 4; ++g) {
            const int r = g * 16 + li;
            const float* wur = mse_u_w + r * DD + q * 16;
            const float* wir = mse_i_w + r * DD + q * 16;
            float fu = 0.f, fi = 0.f;
#pragma unroll
            for (int j = 0; j < 4; ++j) {
                const float4 a = *(const float4*)(wur + j * 4);
                fu = fmaf(a.x, uv[j].x, fu); fu = fmaf(a.y, uv[j].y, fu);
                fu = fmaf(a.z, uv[j].z, fu); fu = fmaf(a.w, uv[j].w, fu);
                const float4 c = *(const float4*)(wir + j * 4);
                fi = fmaf(c.x, pv[j].x, fi); fi = fmaf(c.y, pv[j].y, fi);
                fi = fmaf(c.z, pv[j].z, fi); fi = fmaf(c.w, pv[j].w, fi);
            }
            fu += __shfl_xor(fu, 1, 64); fu += __shfl_xor(fu, 2, 64);
            fi += __shfl_xor(fi, 1, 64); fi += __shfl_xor(fi, 2, 64);
            fu += mse_u_b[r];
            fi += mse_i_b[r];
            pq += fu * fi;
        }
        const float pred = waveReduceSum(pq) * 0.25f;   // 4-lane redundancy
        if (lane == 0) {
            const float diff = pred - rpkms[b];
            accM += diff * diff;
        }
    }

    // ---- block reduce + atomics + ticket finalize ----
    accL = waveReduceSum(accL);
    accI = waveReduceSum(accI);
    __shared__ float redL[4], redI[4], redM[4];
    if (lane == 0) { redL[wave] = accL; redI[wave] = accI; redM[wave] = accM; }
    __syncthreads();
    if (threadIdx.x == 0) {
        atomicAdd(&acc[0], redL[0] + redL[1] + redL[2] + redL[3]);
        atomicAdd(&acc[1], redI[0] + redI[1] + redI[2] + redI[3]);
        atomicAdd(&acc[3], redM[0] + redM[1] + redM[2] + redM[3]);
        __threadfence();
        const unsigned int t = atomicAdd(cnt, 1u);
        if (t == (unsigned int)(gridDim.x - 1)) {
            // all blocks' adds fenced & visible; K1's adds completed before
            // this kernel launched (stream order).
            const float sL  = atomicAdd(&acc[0], 0.0f);
            const float sI  = atomicAdd(&acc[1], 0.0f);
            const float sNo = atomicAdd(&acc[2], 0.0f);
            const float sM  = atomicAdd(&acc[3], 0.0f);
            const float loss_L = sL / (float)BB;
            const float loss_I = 2.5f * sI / (float)(BB * KK);
            const float mse    = sM / (float)BB;
            const float nrm    = 1e-4f * 0.5f * sNo;
            out[0] = loss_L + nrm + loss_I + mse;
            out[1] = loss_L;
            out[2] = loss_I;
            out[3] = 0.0f;
            out[4] = mse;
            out[5] = nrm;
        }
    }
}

// ===========================================================================
// Fallback (ws too small for bf16 table): R2's verified fp32 path
// ===========================================================================
#define NORMB 1024
__global__ __launch_bounds__(256) void fb_fused_kernel(
    const int* __restrict__ users, const int* __restrict__ pos_items,
    const int* __restrict__ neg_items,
    const float* __restrict__ user_emb, const float* __restrict__ item_emb,
    const float* __restrict__ beta_uD, const float* __restrict__ beta_iD,
    const int* __restrict__ ii_nbr, const float* __restrict__ ii_con,
    const float* __restrict__ mse_u_w, const float* __restrict__ mse_u_b,
    const float* __restrict__ mse_i_w, const float* __restrict__ mse_i_b,
    const float* __restrict__ fc1_w1, const float* __restrict__ fc1_b1,
    const float* __restrict__ fc1_w2, const float* __restrict__ fc1_b2,
    float* __restrict__ acc)
{
    const int wave = threadIdx.x >> 6;
    const int lane = threadIdx.x & 63;
    __shared__ float red[4];

    if (blockIdx.x < NORMB) {
        const size_t tid = (size_t)blockIdx.x * blockDim.x + threadIdx.x;
        const size_t st  = (size_t)NORMB * 256;
        const size_t n4  = (size_t)UU * DD / 4;
        float s = 0.f;
        const v4f* a = (const v4f*)user_emb;
        for (size_t i = tid; i < n4; i += st) {
            v4f x = a[i]; s += x.x*x.x + x.y*x.y + x.z*x.z + x.w*x.w;
        }
        const v4f* c = (const v4f*)item_emb;
        for (size_t i = tid; i < n4; i += st) {
            v4f x = c[i]; s += x.x*x.x + x.y*x.y + x.z*x.z + x.w*x.w;
        }
        for (size_t i = tid; i < (size_t)DD * DD; i += st)
            s += mse_u_w[i] * mse_u_w[i] + mse_i_w[i] * mse_i_w[i];
        for (size_t i = tid; i < (size_t)DD * 2 * DD; i += st)
            s += fc1_w1[i] * fc1_w1[i];
        for (size_t i = tid; i < (size_t)DD; i += st)
            s += mse_u_b[i] * mse_u_b[i] + mse_i_b[i] * mse_i_b[i]
               + fc1_b1[i] * fc1_b1[i] + fc1_w2[i] * fc1_w2[i];
        if (tid == 0) s += fc1_b2[0] * fc1_b2[0];
        s = waveReduceSum(s);
        if (lane == 0) red[wave] = s;
        __syncthreads();
        if (threadIdx.x == 0)
            atomicAdd(&acc[2], red[0] + red[1] + red[2] + red[3]);
        return;
    }

    const int b = (blockIdx.x - NORMB) * 4 + wave;
    float accL = 0.f, accI = 0.f;
    const int u_idx = users[b];
    const int p_idx = pos_items[b];
    const float u_reg = user_emb[(size_t)u_idx * DD + lane];
    const float bu = beta_uD[u_idx];
    __shared__ float sU[4][DD];
    sU[wave][lane] = u_reg;
    const int q  = lane & 3;
    const int li = lane >> 2;
    float4 uv[4];
#pragma unroll
    for (int j = 0; j < 4; ++j) uv[j] = *(const float4*)&sU[wave][j * 16 + q * 4];
    {
        const float p = item_emb[(size_t)p_idx * DD + lane];
        const float pos_dot = waveReduceSum(u_reg * p);
        if (lane == 0) accL += (1e-6f + bu * beta_iD[p_idx]) * softplus_f(-pos_dot);
    }
    const int i0 = neg_items[(size_t)b * NNEG + lane];
    const int i1 = neg_items[(size_t)b * NNEG + 64 + lane];
    const float bn0 = beta_iD[i0];
    const float bn1 = beta_iD[i1];
    const float negscale4 = 0.25f * (200.0f / (float)NNEG);
#pragma unroll
    for (int g = 0; g < 2; ++g) {
        const int   srcI = g ? i1 : i0;
        const float srcB = g ? bn1 : bn0;
        float4 vb[4][4]; float bi4[4];
#pragma unroll
        for (int t = 0; t < 4; ++t) {
            const int n = t * 16 + li;
            const int idx = __shfl(srcI, n, 64);
            bi4[t] = __shfl(srcB, n, 64);
            const float* row = item_emb + (size_t)idx * DD + q * 4;
#pragma unroll
            for (int j = 0; j < 4; ++j) vb[t][j] = *(const float4*)(row + j * 16);
        }
#pragma unroll
        for (int t = 0; t < 4; ++t) {
            float dot = 0.f;
#pragma unroll
            for (int j = 0; j < 4; ++j) {
                dot = fmaf(vb[t][j].x, uv[j].x, dot);
                dot = fmaf(vb[t][j].y, uv[j].y, dot);
                dot = fmaf(vb[t][j].z, uv[j].z, dot);
                dot = fmaf(vb[t][j].w, uv[j].w, dot);
            }
            dot += __shfl_xor(dot, 1, 64);
            dot += __shfl_xor(dot, 2, 64);
            accL += negscale4 * (1e-6f + bu * bi4[t]) * softplus_f(dot);
        }
    }
    int nbv = 0; float simv = 0.f;
    if (lane < KK) {
        nbv  = ii_nbr[(size_t)p_idx * KK + lane];
        simv = ii_con[(size_t)p_idx * KK + lane];
    }
    {
        float4 vb[2][4]; float sk2[2];
#pragma unroll
        for (int t = 0; t < 2; ++t) {
            const int n = t * 16 + li;
            const int idx = __shfl(nbv, n, 64);
            sk2[t] = __shfl(simv, n, 64);
            const float* row = item_emb + (size_t)idx * DD + q * 4;
#pragma unroll
            for (int j = 0; j < 4; ++j) vb[t][j] = *(const float4*)(row + j * 16);
        }
#pragma unroll
        for (int t = 0; t < 2; ++t) {
            float dot = 0.f;
#pragma unroll
            for (int j = 0; j < 4; ++j) {
                dot = fmaf(vb[t][j].x, uv[j].x, dot);
                dot = fmaf(vb[t][j].y, uv[j].y, dot);
                dot = fmaf(vb[t][j].z, uv[j].z, dot);
                dot = fmaf(vb[t][j].w, uv[j].w, dot);
            }
            dot += __shfl_xor(dot, 1, 64);
            dot += __shfl_xor(dot, 2, 64);
            accI += 0.25f * sk2[t] * softplus_f(-dot);
        }
    }
    accL = waveReduceSum(accL);
    accI = waveReduceSum(accI);
    __shared__ float redL[4], redI[4];
    if (lane == 0) { redL[wave] = accL; redI[wave] = accI; }
    __syncthreads();
    if (threadIdx.x == 0) {
        atomicAdd(&acc[0], redL[0] + redL[1] + redL[2] + redL[3]);
        atomicAdd(&acc[1], redI[0] + redI[1] + redI[2] + redI[3]);
    }
}

__global__ __launch_bounds__(256) void fb_mse_kernel(
    const int* __restrict__ users, const int* __restrict__ pos_items,
    const float* __restrict__ rpkms,
    const float* __restrict__ user_emb, const float* __restrict__ item_emb,
    const float* __restrict__ mse_u_w, const float* __restrict__ mse_u_b,
    const float* __restrict__ mse_i_w, const float* __restrict__ mse_i_b,
    float* __restrict__ acc)
{
    __shared__ float sWu[DD * (DD + 1)];
    __shared__ float sWi[DD * (DD + 1)];
    __shared__ float sBu[DD], sBi[DD];
    __shared__ float sUe[4][DD], sPe[4][DD];
    for (int i = threadIdx.x; i < DD * DD; i += blockDim.x) {
        const int r = i >> 6, c = i & 63;
        sWu[r * (DD + 1) + c] = mse_u_w[i];
        sWi[r * (DD + 1) + c] = mse_i_w[i];
    }
    if (threadIdx.x < DD) {
        sBu[threadIdx.x] = mse_u_b[threadIdx.x];
        sBi[threadIdx.x] = mse_i_b[threadIdx.x];
    }
    const int wave = threadIdx.x >> 6;
    const int lane = threadIdx.x & 63;
    const int b = blockIdx.x * 4 + wave;
    sUe[wave][lane] = user_emb[(size_t)users[b] * DD + lane];
    sPe[wave][lane] = item_emb[(size_t)pos_items[b] * DD + lane];
    __syncthreads();
    float fu = sBu[lane];
    float fi = sBi[lane];
#pragma unroll 8
    for (int d = 0; d < DD; ++d) {
        fu += sUe[wave][d] * sWu[lane * (DD + 1) + d];
        fi += sPe[wave][d] * sWi[lane * (DD + 1) + d];
    }
    const float pred = waveReduceSum(fu * fi);
    if (lane == 0) {
        const float diff = pred - rpkms[b];
        atomicAdd(&acc[3], diff * diff);
    }
}

// ---------------- finalize (fallback path only) ----------------
__global__ void finalize_kernel(const float* __restrict__ acc, float* __restrict__ out)
{
    if (threadIdx.x == 0) {
        const float loss_L = acc[0] / (float)BB;
        const float loss_I = 2.5f * acc[1] / (float)(BB * KK);
        const float mse    = acc[3] / (float)BB;
        const float norm   = 1e-4f * 0.5f * acc[2];
        const float total  = loss_L + norm + loss_I + mse;
        out[0] = total;
        out[1] = loss_L;
        out[2] = loss_I;
        out[3] = 0.0f;
        out[4] = mse;
        out[5] = norm;
    }
}

extern "C" void kernel_launch(void* const* d_in, const int* in_sizes, int n_in,
                              void* d_out, int out_size, void* d_ws, size_t ws_size,
                              hipStream_t stream)
{
    const int*   users      = (const int*)  d_in[0];
    const int*   pos_items  = (const int*)  d_in[1];
    const int*   neg_items  = (const int*)  d_in[2];
    const float* rpkms      = (const float*)d_in[3];
    const float* user_emb   = (const float*)d_in[4];
    const float* item_emb   = (const float*)d_in[5];
    const float* beta_uD    = (const float*)d_in[6];
    const float* beta_iD    = (const float*)d_in[7];
    const int*   ii_nbr     = (const int*)  d_in[8];
    const float* ii_con     = (const float*)d_in[9];
    const float* mse_u_w    = (const float*)d_in[10];
    const float* mse_u_b    = (const float*)d_in[11];
    const float* mse_i_w    = (const float*)d_in[12];
    const float* mse_i_b    = (const float*)d_in[13];
    const float* fc1_w1     = (const float*)d_in[14];
    const float* fc1_b1     = (const float*)d_in[15];
    const float* fc1_w2     = (const float*)d_in[16];
    const float* fc1_b2     = (const float*)d_in[17];

    float* acc = (float*)d_ws;                      // [0..3] loss sums
    unsigned int* cnt = (unsigned int*)d_ws + 4;    // [4] block ticket
    hipMemsetAsync(d_ws, 0, 8 * sizeof(float), stream);

    const size_t bf_bytes = (size_t)II * DD * 2;    // 64 MB bf16 table
    const size_t need = 256 + bf_bytes;

    if (ws_size >= need) {
        unsigned int* bfit = (unsigned int*)((char*)d_ws + 256);
        norm_convert_kernel<<<4096, 256, 0, stream>>>(
            user_emb, item_emb, bfit,
            mse_u_w, mse_u_b, mse_i_w, mse_i_b,
            fc1_w1, fc1_b1, fc1_w2, fc1_b2, acc);
        gather_split_kernel<<<BB / 2, 256, 0, stream>>>(
            users, pos_items, neg_items, rpkms,
            user_emb, item_emb, bfit, beta_uD, beta_iD,
            ii_nbr, ii_con, mse_u_w, mse_u_b, mse_i_w, mse_i_b,
            acc, cnt, (float*)d_out);
    } else {
        fb_fused_kernel<<<NORMB + BB / 4, 256, 0, stream>>>(
            users, pos_items, neg_items,
            user_emb, item_emb, beta_uD, beta_iD, ii_nbr, ii_con,
            mse_u_w, mse_u_b, mse_i_w, mse_i_b,
            fc1_w1, fc1_b1, fc1_w2, fc1_b2, acc);
        fb_mse_kernel<<<BB / 4, 256, 0, stream>>>(
            users, pos_items, rpkms, user_emb, item_emb,
            mse_u_w, mse_u_b, mse_i_w, mse_i_b, acc);
        finalize_kernel<<<1, 64, 0, stream>>>(acc, (float*)d_out);
    }
}

// Round 3
// 504.068 us; speedup vs baseline: 1.2292x; 1.2292x over previous
//
#include <hip/hip_runtime.h>
#include <math.h>

// Problem constants (match reference)
#define UU 500000
#define II 500000
#define DD 64
#define KK 32
#define BB 8192
#define NNEG 128

typedef float v4f __attribute__((ext_vector_type(4)));
typedef float v2f __attribute__((ext_vector_type(2)));

__device__ __forceinline__ float softplus_f(float x) {
    return fmaxf(x, 0.0f) + log1pf(expf(-fabsf(x)));
}

__device__ __forceinline__ float waveReduceSum(float v) {
#pragma unroll
    for (int off = 32; off > 0; off >>= 1) v += __shfl_xor(v, off, 64);
    return v;
}

// ===========================================================================
// K1: norm over all params (fp32) + convert item_emb -> fp8(e4m3, x64) table.
// Pure streaming, all CUs. 4096 blocks x 256. (R0-proven structure; only the
// pack format changed: HW cvt_pk_fp8_f32, scale 64 so values are e4m3-normal.)
// ===========================================================================
__global__ __launch_bounds__(256) void norm_convert_kernel(
    const float* __restrict__ user_emb, const float* __restrict__ item_emb,
    unsigned int* __restrict__ f8it,    // II rows * 64 B = II*16 uints (32 MB)
    const float* __restrict__ mse_u_w, const float* __restrict__ mse_u_b,
    const float* __restrict__ mse_i_w, const float* __restrict__ mse_i_b,
    const float* __restrict__ fc1_w1, const float* __restrict__ fc1_b1,
    const float* __restrict__ fc1_w2, const float* __restrict__ fc1_b2,
    float* __restrict__ acc)
{
    const size_t tid = (size_t)blockIdx.x * blockDim.x + threadIdx.x;
    const size_t st  = (size_t)gridDim.x * blockDim.x;
    float s = 0.f;

    // ---- item_emb: read fp32 (NT), accumulate squares, write fp8 x64 ----
    {
        const size_t n16 = (size_t)II * DD / 16;   // 2M: 4 float4 -> one uint4
        const v4f* it4 = (const v4f*)item_emb;
        uint4* out4 = (uint4*)f8it;
        for (size_t k = tid; k < n16; k += st) {
            v4f a = __builtin_nontemporal_load(&it4[4 * k]);
            v4f b = __builtin_nontemporal_load(&it4[4 * k + 1]);
            v4f c = __builtin_nontemporal_load(&it4[4 * k + 2]);
            v4f d = __builtin_nontemporal_load(&it4[4 * k + 3]);
            s += a.x*a.x + a.y*a.y + a.z*a.z + a.w*a.w;
            s += b.x*b.x + b.y*b.y + b.z*b.z + b.w*b.w;
            s += c.x*c.x + c.y*c.y + c.z*c.z + c.w*c.w;
            s += d.x*d.x + d.y*d.y + d.z*d.z + d.w*d.w;
            uint4 w;
            w.x = __builtin_amdgcn_cvt_pk_fp8_f32(a.x * 64.f, a.y * 64.f, 0u,  false);
            w.x = __builtin_amdgcn_cvt_pk_fp8_f32(a.z * 64.f, a.w * 64.f, w.x, true);
            w.y = __builtin_amdgcn_cvt_pk_fp8_f32(b.x * 64.f, b.y * 64.f, 0u,  false);
            w.y = __builtin_amdgcn_cvt_pk_fp8_f32(b.z * 64.f, b.w * 64.f, w.y, true);
            w.z = __builtin_amdgcn_cvt_pk_fp8_f32(c.x * 64.f, c.y * 64.f, 0u,  false);
            w.z = __builtin_amdgcn_cvt_pk_fp8_f32(c.z * 64.f, c.w * 64.f, w.z, true);
            w.w = __builtin_amdgcn_cvt_pk_fp8_f32(d.x * 64.f, d.y * 64.f, 0u,  false);
            w.w = __builtin_amdgcn_cvt_pk_fp8_f32(d.z * 64.f, d.w * 64.f, w.w, true);
            out4[k] = w;   // normal store: want it L2/LLC resident for K2
        }
    }
    // ---- user_emb: squares only ----
    {
        const size_t n4 = (size_t)UU * DD / 4;
        const v4f* a = (const v4f*)user_emb;
        for (size_t i = tid; i < n4; i += st) {
            v4f x = __builtin_nontemporal_load(&a[i]);
            s += x.x*x.x + x.y*x.y + x.z*x.z + x.w*x.w;
        }
    }
    // ---- small params ----
    for (size_t i = tid; i < (size_t)DD * DD; i += st)
        s += mse_u_w[i] * mse_u_w[i] + mse_i_w[i] * mse_i_w[i];
    for (size_t i = tid; i < (size_t)DD * 2 * DD; i += st)
        s += fc1_w1[i] * fc1_w1[i];
    for (size_t i = tid; i < (size_t)DD; i += st)
        s += mse_u_b[i] * mse_u_b[i] + mse_i_b[i] * mse_i_b[i]
           + fc1_b1[i] * fc1_b1[i] + fc1_w2[i] * fc1_w2[i];
    if (tid == 0) s += fc1_b2[0] * fc1_b2[0];

    s = waveReduceSum(s);
    __shared__ float red[4];
    if ((threadIdx.x & 63) == 0) red[threadIdx.x >> 6] = s;
    __syncthreads();
    if (threadIdx.x == 0)
        atomicAdd(&acc[2], red[0] + red[1] + red[2] + red[3]);
}

// ===========================================================================
// K2: gather loss_L + loss_I from fp8 table, fused mse + ticket finalize.
// One wave per b (R0-proven). 4 lanes per item; fp8 row = 64 B = ONE 16B
// load per lane. 10 gather groups, ring depth 4 (64 rows in flight/wave).
// VGPR must stay <= 64 (8 waves/SIMD) — no min-waves bound (R2 lesson).
// ===========================================================================
__global__ __launch_bounds__(256) void gather_mse_kernel(
    const int* __restrict__ users, const int* __restrict__ pos_items,
    const int* __restrict__ neg_items, const float* __restrict__ rpkms,
    const float* __restrict__ user_emb, const float* __restrict__ item_emb,
    const unsigned int* __restrict__ f8it,
    const float* __restrict__ beta_uD, const float* __restrict__ beta_iD,
    const int* __restrict__ ii_nbr, const float* __restrict__ ii_con,
    const float* __restrict__ mse_u_w, const float* __restrict__ mse_u_b,
    const float* __restrict__ mse_i_w, const float* __restrict__ mse_i_b,
    float* __restrict__ acc, unsigned int* __restrict__ cnt,
    float* __restrict__ out)
{
    const int wave = threadIdx.x >> 6;
    const int lane = threadIdx.x & 63;
    const int b = blockIdx.x * 4 + wave;

    const int u_idx = users[b];
    const int p_idx = pos_items[b];
    const float u_reg = user_emb[(size_t)u_idx * DD + lane];
    const float p_reg = item_emb[(size_t)p_idx * DD + lane];   // pos row fp32
    const float bu = beta_uD[u_idx];

    __shared__ float sU[4][DD];
    __shared__ float sP[4][DD];
    sU[wave][lane] = u_reg;    // wave-synchronous
    sP[wave][lane] = p_reg;

    const int q  = lane & 3;   // quarter within item (16 dims)
    const int li = lane >> 2;  // item within 16-item group

    // lane's u fragment: dims [q*16, q*16+16)
    float4 uv[4];
#pragma unroll
    for (int j = 0; j < 4; ++j)
        uv[j] = *(const float4*)&sU[wave][q * 16 + j * 4];

    float accL = 0.f, accI = 0.f, accM = 0.f;

    // ---- pos score (fp32 exact) ----
    {
        const float pos_dot = waveReduceSum(u_reg * p_reg);
        if (lane == 0)
            accL += (1e-6f + bu * beta_iD[p_idx]) * softplus_f(-pos_dot);
    }

    // ---- preload indices/weights (lane-resident, broadcast via shfl) ----
    const int i0 = neg_items[(size_t)b * NNEG + lane];
    const int i1 = neg_items[(size_t)b * NNEG + 64 + lane];
    const float bn0 = beta_iD[i0];
    const float bn1 = beta_iD[i1];
    int nbv = 0; float simv = 0.f;
    if (lane < KK) {
        nbv  = ii_nbr[(size_t)p_idx * KK + lane];
        simv = ii_con[(size_t)p_idx * KK + lane];
    }

    const float negscale4 = 0.25f * (200.0f / (float)NNEG);
    const float inv64 = 0.015625f;   // exact 1/64: undo table scale

    // ring buffers for pipelined gather (depth 4): one uint4 = full 16-dim slice
    uint4 rg[4];
    float rw[4];

#define PREP(g, slot)                                                          \
    {                                                                          \
        int idx; float w;                                                      \
        if ((g) < 4)      { idx = __shfl(i0, (g) * 16 + li, 64);               \
                            w   = __shfl(bn0, (g) * 16 + li, 64); }            \
        else if ((g) < 8) { idx = __shfl(i1, ((g) - 4) * 16 + li, 64);         \
                            w   = __shfl(bn1, ((g) - 4) * 16 + li, 64); }      \
        else              { idx = __shfl(nbv, ((g) - 8) * 16 + li, 64);        \
                            w   = __shfl(simv, ((g) - 8) * 16 + li, 64); }     \
        rg[slot] = ((const uint4*)(f8it + (size_t)idx * (DD / 4)))[q];         \
        rw[slot] = w;                                                          \
    }

#define DOT4(u32, vv, d)                                                       \
    {                                                                          \
        v2f lo = __builtin_amdgcn_cvt_pk_f32_fp8((u32), false);                \
        v2f hi = __builtin_amdgcn_cvt_pk_f32_fp8((u32), true);                 \
        d = fmaf(lo.x, (vv).x, d); d = fmaf(lo.y, (vv).y, d);                  \
        d = fmaf(hi.x, (vv).z, d); d = fmaf(hi.y, (vv).w, d);                  \
    }

#define CONSUME(g, slot)                                                       \
    {                                                                          \
        float dot = 0.f;                                                       \
        DOT4(rg[slot].x, uv[0], dot);                                          \
        DOT4(rg[slot].y, uv[1], dot);                                          \
        DOT4(rg[slot].z, uv[2], dot);                                          \
        DOT4(rg[slot].w, uv[3], dot);                                          \
        dot *= inv64;                                                          \
        dot += __shfl_xor(dot, 1, 64);                                         \
        dot += __shfl_xor(dot, 2, 64);                                         \
        if ((g) < 8) accL += negscale4 * (1e-6f + bu * rw[slot]) * softplus_f(dot); \
        else         accI += 0.25f * rw[slot] * softplus_f(-dot);              \
    }

    PREP(0, 0); PREP(1, 1); PREP(2, 2); PREP(3, 3);
    CONSUME(0, 0); PREP(4, 0);
    CONSUME(1, 1); PREP(5, 1);
    CONSUME(2, 2); PREP(6, 2);
    CONSUME(3, 3); PREP(7, 3);
    CONSUME(4, 0); PREP(8, 0);
    CONSUME(5, 1); PREP(9, 1);
    CONSUME(6, 2);
    CONSUME(7, 3);
    CONSUME(8, 0);
    CONSUME(9, 1);
#undef PREP
#undef DOT4
#undef CONSUME

    // ---- fused mse: feat_u = Wu@u + bu_, feat_i = Wi@p + bi_, pred = <fu,fi> ----
    {
        float4 pv[4];
#pragma unroll
        for (int j = 0; j < 4; ++j)
            pv[j] = *(const float4*)&sP[wave][q * 16 + j * 4];
        float pq = 0.f;
#pragma unroll
        for (int g = 0; g < 4; ++g) {
            const int r = g * 16 + li;
            const float* wur = mse_u_w + r * DD + q * 16;
            const float* wir = mse_i_w + r * DD + q * 16;
            float fu = 0.f, fi = 0.f;
#pragma unroll
            for (int j = 0; j < 4; ++j) {
                const float4 a = *(const float4*)(wur + j * 4);
                fu = fmaf(a.x, uv[j].x, fu); fu = fmaf(a.y, uv[j].y, fu);
                fu = fmaf(a.z, uv[j].z, fu); fu = fmaf(a.w, uv[j].w, fu);
                const float4 c = *(const float4*)(wir + j * 4);
                fi = fmaf(c.x, pv[j].x, fi); fi = fmaf(c.y, pv[j].y, fi);
                fi = fmaf(c.z, pv[j].z, fi); fi = fmaf(c.w, pv[j].w, fi);
            }
            fu += __shfl_xor(fu, 1, 64); fu += __shfl_xor(fu, 2, 64);
            fi += __shfl_xor(fi, 1, 64); fi += __shfl_xor(fi, 2, 64);
            fu += mse_u_b[r];
            fi += mse_i_b[r];
            pq += fu * fi;
        }
        const float pred = waveReduceSum(pq) * 0.25f;   // 4-lane redundancy
        if (lane == 0) {
            const float diff = pred - rpkms[b];
            accM += diff * diff;
        }
    }

    // ---- block reduce + atomics + ticket finalize ----
    accL = waveReduceSum(accL);
    accI = waveReduceSum(accI);
    __shared__ float redL[4], redI[4], redM[4];
    if (lane == 0) { redL[wave] = accL; redI[wave] = accI; redM[wave] = accM; }
    __syncthreads();
    if (threadIdx.x == 0) {
        atomicAdd(&acc[0], redL[0] + redL[1] + redL[2] + redL[3]);
        atomicAdd(&acc[1], redI[0] + redI[1] + redI[2] + redI[3]);
        atomicAdd(&acc[3], redM[0] + redM[1] + redM[2] + redM[3]);
        __threadfence();
        const unsigned int t = atomicAdd(cnt, 1u);
        if (t == (unsigned int)(gridDim.x - 1)) {
            // all blocks' adds fenced & visible; K1's adds completed before
            // this kernel launched (stream order).
            const float sL  = atomicAdd(&acc[0], 0.0f);
            const float sI  = atomicAdd(&acc[1], 0.0f);
            const float sNo = atomicAdd(&acc[2], 0.0f);
            const float sM  = atomicAdd(&acc[3], 0.0f);
            const float loss_L = sL / (float)BB;
            const float loss_I = 2.5f * sI / (float)(BB * KK);
            const float mse    = sM / (float)BB;
            const float nrm    = 1e-4f * 0.5f * sNo;
            out[0] = loss_L + nrm + loss_I + mse;
            out[1] = loss_L;
            out[2] = loss_I;
            out[3] = 0.0f;
            out[4] = mse;
            out[5] = nrm;
        }
    }
}

// ===========================================================================
// Fallback (ws too small for fp8 table): verified fp32 path
// ===========================================================================
#define NORMB 1024
__global__ __launch_bounds__(256) void fb_fused_kernel(
    const int* __restrict__ users, const int* __restrict__ pos_items,
    const int* __restrict__ neg_items,
    const float* __restrict__ user_emb, const float* __restrict__ item_emb,
    const float* __restrict__ beta_uD, const float* __restrict__ beta_iD,
    const int* __restrict__ ii_nbr, const float* __restrict__ ii_con,
    const float* __restrict__ mse_u_w, const float* __restrict__ mse_u_b,
    const float* __restrict__ mse_i_w, const float* __restrict__ mse_i_b,
    const float* __restrict__ fc1_w1, const float* __restrict__ fc1_b1,
    const float* __restrict__ fc1_w2, const float* __restrict__ fc1_b2,
    float* __restrict__ acc)
{
    const int wave = threadIdx.x >> 6;
    const int lane = threadIdx.x & 63;
    __shared__ float red[4];

    if (blockIdx.x < NORMB) {
        const size_t tid = (size_t)blockIdx.x * blockDim.x + threadIdx.x;
        const size_t st  = (size_t)NORMB * 256;
        const size_t n4  = (size_t)UU * DD / 4;
        float s = 0.f;
        const v4f* a = (const v4f*)user_emb;
        for (size_t i = tid; i < n4; i += st) {
            v4f x = a[i]; s += x.x*x.x + x.y*x.y + x.z*x.z + x.w*x.w;
        }
        const v4f* c = (const v4f*)item_emb;
        for (size_t i = tid; i < n4; i += st) {
            v4f x = c[i]; s += x.x*x.x + x.y*x.y + x.z*x.z + x.w*x.w;
        }
        for (size_t i = tid; i < (size_t)DD * DD; i += st)
            s += mse_u_w[i] * mse_u_w[i] + mse_i_w[i] * mse_i_w[i];
        for (size_t i = tid; i < (size_t)DD * 2 * DD; i += st)
            s += fc1_w1[i] * fc1_w1[i];
        for (size_t i = tid; i < (size_t)DD; i += st)
            s += mse_u_b[i] * mse_u_b[i] + mse_i_b[i] * mse_i_b[i]
               + fc1_b1[i] * fc1_b1[i] + fc1_w2[i] * fc1_w2[i];
        if (tid == 0) s += fc1_b2[0] * fc1_b2[0];
        s = waveReduceSum(s);
        if (lane == 0) red[wave] = s;
        __syncthreads();
        if (threadIdx.x == 0)
            atomicAdd(&acc[2], red[0] + red[1] + red[2] + red[3]);
        return;
    }

    const int b = (blockIdx.x - NORMB) * 4 + wave;
    float accL = 0.f, accI = 0.f;
    const int u_idx = users[b];
    const int p_idx = pos_items[b];
    const float u_reg = user_emb[(size_t)u_idx * DD + lane];
    const float bu = beta_uD[u_idx];
    __shared__ float sU[4][DD];
    sU[wave][lane] = u_reg;
    const int q  = lane & 3;
    const int li = lane >> 2;
    float4 uv[4];
#pragma unroll
    for (int j = 0; j < 4; ++j) uv[j] = *(const float4*)&sU[wave][j * 16 + q * 4];
    {
        const float p = item_emb[(size_t)p_idx * DD + lane];
        const float pos_dot = waveReduceSum(u_reg * p);
        if (lane == 0) accL += (1e-6f + bu * beta_iD[p_idx]) * softplus_f(-pos_dot);
    }
    const int i0 = neg_items[(size_t)b * NNEG + lane];
    const int i1 = neg_items[(size_t)b * NNEG + 64 + lane];
    const float bn0 = beta_iD[i0];
    const float bn1 = beta_iD[i1];
    const float negscale4 = 0.25f * (200.0f / (float)NNEG);
#pragma unroll
    for (int g = 0; g < 2; ++g) {
        const int   srcI = g ? i1 : i0;
        const float srcB = g ? bn1 : bn0;
        float4 vb[4][4]; float bi4[4];
#pragma unroll
        for (int t = 0; t < 4; ++t) {
            const int n = t * 16 + li;
            const int idx = __shfl(srcI, n, 64);
            bi4[t] = __shfl(srcB, n, 64);
            const float* row = item_emb + (size_t)idx * DD + q * 4;
#pragma unroll
            for (int j = 0; j < 4; ++j) vb[t][j] = *(const float4*)(row + j * 16);
        }
#pragma unroll
        for (int t = 0; t < 4; ++t) {
            float dot = 0.f;
#pragma unroll
            for (int j = 0; j < 4; ++j) {
                dot = fmaf(vb[t][j].x, uv[j].x, dot);
                dot = fmaf(vb[t][j].y, uv[j].y, dot);
                dot = fmaf(vb[t][j].z, uv[j].z, dot);
                dot = fmaf(vb[t][j].w, uv[j].w, dot);
            }
            dot += __shfl_xor(dot, 1, 64);
            dot += __shfl_xor(dot, 2, 64);
            accL += negscale4 * (1e-6f + bu * bi4[t]) * softplus_f(dot);
        }
    }
    int nbv = 0; float simv = 0.f;
    if (lane < KK) {
        nbv  = ii_nbr[(size_t)p_idx * KK + lane];
        simv = ii_con[(size_t)p_idx * KK + lane];
    }
    {
        float4 vb[2][4]; float sk2[2];
#pragma unroll
        for (int t = 0; t < 2; ++t) {
            const int n = t * 16 + li;
            const int idx = __shfl(nbv, n, 64);
            sk2[t] = __shfl(simv, n, 64);
            const float* row = item_emb + (size_t)idx * DD + q * 4;
#pragma unroll
            for (int j = 0; j < 4; ++j) vb[t][j] = *(const float4*)(row + j * 16);
        }
#pragma unroll
        for (int t = 0; t < 2; ++t) {
            float dot = 0.f;
#pragma unroll
            for (int j = 0; j < 4; ++j) {
                dot = fmaf(vb[t][j].x, uv[j].x, dot);
                dot = fmaf(vb[t][j].y, uv[j].y, dot);
                dot = fmaf(vb[t][j].z, uv[j].z, dot);
                dot = fmaf(vb[t][j].w, uv[j].w, dot);
            }
            dot += __shfl_xor(dot, 1, 64);
            dot += __shfl_xor(dot, 2, 64);
            accI += 0.25f * sk2[t] * softplus_f(-dot);
        }
    }
    accL = waveReduceSum(accL);
    accI = waveReduceSum(accI);
    __shared__ float redL[4], redI[4];
    if (lane == 0) { redL[wave] = accL; redI[wave] = accI; }
    __syncthreads();
    if (threadIdx.x == 0) {
        atomicAdd(&acc[0], redL[0] + redL[1] + redL[2] + redL[3]);
        atomicAdd(&acc[1], redI[0] + redI[1] + redI[2] + redI[3]);
    }
}

__global__ __launch_bounds__(256) void fb_mse_kernel(
    const int* __restrict__ users, const int* __restrict__ pos_items,
    const float* __restrict__ rpkms,
    const float* __restrict__ user_emb, const float* __restrict__ item_emb,
    const float* __restrict__ mse_u_w, const float* __restrict__ mse_u_b,
    const float* __restrict__ mse_i_w, const float* __restrict__ mse_i_b,
    float* __restrict__ acc)
{
    __shared__ float sWu[DD * (DD + 1)];
    __shared__ float sWi[DD * (DD + 1)];
    __shared__ float sBu[DD], sBi[DD];
    __shared__ float sUe[4][DD], sPe[4][DD];
    for (int i = threadIdx.x; i < DD * DD; i += blockDim.x) {
        const int r = i >> 6, c = i & 63;
        sWu[r * (DD + 1) + c] = mse_u_w[i];
        sWi[r * (DD + 1) + c] = mse_i_w[i];
    }
    if (threadIdx.x < DD) {
        sBu[threadIdx.x] = mse_u_b[threadIdx.x];
        sBi[threadIdx.x] = mse_i_b[threadIdx.x];
    }
    const int wave = threadIdx.x >> 6;
    const int lane = threadIdx.x & 63;
    const int b = blockIdx.x * 4 + wave;
    sUe[wave][lane] = user_emb[(size_t)users[b] * DD + lane];
    sPe[wave][lane] = item_emb[(size_t)pos_items[b] * DD + lane];
    __syncthreads();
    float fu = sBu[lane];
    float fi = sBi[lane];
#pragma unroll 8
    for (int d = 0; d < DD; ++d) {
        fu += sUe[wave][d] * sWu[lane * (DD + 1) + d];
        fi += sPe[wave][d] * sWi[lane * (DD + 1) + d];
    }
    const float pred = waveReduceSum(fu * fi);
    if (lane == 0) {
        const float diff = pred - rpkms[b];
        atomicAdd(&acc[3], diff * diff);
    }
}

// ---------------- finalize (fallback path only) ----------------
__global__ void finalize_kernel(const float* __restrict__ acc, float* __restrict__ out)
{
    if (threadIdx.x == 0) {
        const float loss_L = acc[0] / (float)BB;
        const float loss_I = 2.5f * acc[1] / (float)(BB * KK);
        const float mse    = acc[3] / (float)BB;
        const float norm   = 1e-4f * 0.5f * acc[2];
        const float total  = loss_L + norm + loss_I + mse;
        out[0] = total;
        out[1] = loss_L;
        out[2] = loss_I;
        out[3] = 0.0f;
        out[4] = mse;
        out[5] = norm;
    }
}

extern "C" void kernel_launch(void* const* d_in, const int* in_sizes, int n_in,
                              void* d_out, int out_size, void* d_ws, size_t ws_size,
                              hipStream_t stream)
{
    const int*   users      = (const int*)  d_in[0];
    const int*   pos_items  = (const int*)  d_in[1];
    const int*   neg_items  = (const int*)  d_in[2];
    const float* rpkms      = (const float*)d_in[3];
    const float* user_emb   = (const float*)d_in[4];
    const float* item_emb   = (const float*)d_in[5];
    const float* beta_uD    = (const float*)d_in[6];
    const float* beta_iD    = (const float*)d_in[7];
    const int*   ii_nbr     = (const int*)  d_in[8];
    const float* ii_con     = (const float*)d_in[9];
    const float* mse_u_w    = (const float*)d_in[10];
    const float* mse_u_b    = (const float*)d_in[11];
    const float* mse_i_w    = (const float*)d_in[12];
    const float* mse_i_b    = (const float*)d_in[13];
    const float* fc1_w1     = (const float*)d_in[14];
    const float* fc1_b1     = (const float*)d_in[15];
    const float* fc1_w2     = (const float*)d_in[16];
    const float* fc1_b2     = (const float*)d_in[17];

    float* acc = (float*)d_ws;                      // [0..3] loss sums
    unsigned int* cnt = (unsigned int*)d_ws + 4;    // [4] block ticket
    hipMemsetAsync(d_ws, 0, 8 * sizeof(float), stream);

    const size_t f8_bytes = (size_t)II * DD;        // 32 MB fp8 table
    const size_t need = 256 + f8_bytes;

    if (ws_size >= need) {
        unsigned int* f8it = (unsigned int*)((char*)d_ws + 256);
        norm_convert_kernel<<<4096, 256, 0, stream>>>(
            user_emb, item_emb, f8it,
            mse_u_w, mse_u_b, mse_i_w, mse_i_b,
            fc1_w1, fc1_b1, fc1_w2, fc1_b2, acc);
        gather_mse_kernel<<<BB / 4, 256, 0, stream>>>(
            users, pos_items, neg_items, rpkms,
            user_emb, item_emb, f8it, beta_uD, beta_iD,
            ii_nbr, ii_con, mse_u_w, mse_u_b, mse_i_w, mse_i_b,
            acc, cnt, (float*)d_out);
    } else {
        fb_fused_kernel<<<NORMB + BB / 4, 256, 0, stream>>>(
            users, pos_items, neg_items,
            user_emb, item_emb, beta_uD, beta_iD, ii_nbr, ii_con,
            mse_u_w, mse_u_b, mse_i_w, mse_i_b,
            fc1_w1, fc1_b1, fc1_w2, fc1_b2, acc);
        fb_mse_kernel<<<BB / 4, 256, 0, stream>>>(
            users, pos_items, rpkms, user_emb, item_emb,
            mse_u_w, mse_u_b, mse_i_w, mse_i_b, acc);
        finalize_kernel<<<1, 64, 0, stream>>>(acc, (float*)d_out);
    }
}